// Round 1
// baseline (156.132 us; speedup 1.0000x reference)
//
#include <hip/hip_runtime.h>
#include <math.h>

#define BB 4
#define NN 512
#define FIN 256
#define NH 8
#define FD 32
#define HF 256               // NH * FD
#define NEG 0.21f
#define MASKV (-1000000.0f)
#define LOG2E 1.4426950408889634f

// ---------------------------------------------------------------------------
// Kernel 1: dual GEMM  g = h @ W   (rows = B*N = 2048, K = 256, cols = 256)
// 8 rows per block, one W matrix per blockIdx.y. h tile staged transposed in
// LDS; inner-loop reads are wave-uniform broadcasts (free on 32-bank LDS).
// ---------------------------------------------------------------------------
__global__ __launch_bounds__(256) void gemm_dual(
    const float* __restrict__ h, const float* __restrict__ Wl,
    const float* __restrict__ Wr, float* __restrict__ gl,
    float* __restrict__ gr) {
  __shared__ float ht[FIN][8];  // [k][r], rows of 32B -> float4 aligned
  const int t = threadIdx.x;
  const int row0 = blockIdx.x * 8;
  const float* __restrict__ W = blockIdx.y ? Wr : Wl;
  float* __restrict__ g = blockIdx.y ? gr : gl;

  {  // stage: lds index = t + 256*s  (consecutive across lanes, no conflicts)
    const int r = t & 7;
    const int kb = t >> 3;  // 0..31
    const float* hp = h + (size_t)(row0 + r) * FIN + kb;
#pragma unroll
    for (int s = 0; s < 8; ++s) ht[kb + 32 * s][r] = hp[32 * s];
  }
  __syncthreads();

  float acc[8];
#pragma unroll
  for (int r = 0; r < 8; ++r) acc[r] = 0.f;

  const float* Wp = W + t;  // column t, coalesced across lanes
#pragma unroll 4
  for (int k = 0; k < FIN; ++k) {
    const float w = Wp[(size_t)k * HF];
    const float4 a = *(const float4*)&ht[k][0];
    const float4 b = *(const float4*)&ht[k][4];
    acc[0] = fmaf(a.x, w, acc[0]);
    acc[1] = fmaf(a.y, w, acc[1]);
    acc[2] = fmaf(a.z, w, acc[2]);
    acc[3] = fmaf(a.w, w, acc[3]);
    acc[4] = fmaf(b.x, w, acc[4]);
    acc[5] = fmaf(b.y, w, acc[5]);
    acc[6] = fmaf(b.z, w, acc[6]);
    acc[7] = fmaf(b.w, w, acc[7]);
  }

  float* gp = g + (size_t)row0 * HF + t;
#pragma unroll
  for (int r = 0; r < 8; ++r) gp[(size_t)r * HF] = acc[r];
}

// ---------------------------------------------------------------------------
// Kernel 2: fused GATv2 attention. Block = (head hh, 16-row i-tile, batch b).
//   phase 1: e[ii][j] = sum_f w_f * leaky(g_l[b,j,hh,f] + g_r[b,i0+ii,hh,f])
//            masked by adj -> LDS (stride NN+1 to avoid bank conflicts)
//   phase 2: row softmax (16-lane shuffle reductions), p stored in-place
//   phase 3: out[ii][f] = (sum_j p[ii][j] * g_r[b,j,hh,f]) / l[ii]
// ---------------------------------------------------------------------------
__global__ __launch_bounds__(256) void gat_attn(
    const float* __restrict__ gl, const float* __restrict__ gr,
    const int* __restrict__ adj, const float* __restrict__ aw,
    float* __restrict__ out) {
  __shared__ float e_s[16][NN + 1];  // 16 x 513 floats = 32.8 KB
  __shared__ float q_s[16][36];      // row stride 36 floats = 144B (16B-mult)
  __shared__ float w_s[FD];
  __shared__ float inv_l[16];

  const int t = threadIdx.x;
  const int hh = blockIdx.x;       // 0..7
  const int i0 = blockIdx.y * 16;  // i-tile
  const int b = blockIdx.z;        // 0..3

  if (t < FD) w_s[t] = aw[t];
  if (t < 128) {  // stage query-side g_r rows (16 x 32 floats)
    const int ii = t >> 3, f4 = t & 7;
    const float* p =
        gr + (size_t)(b * NN + i0 + ii) * HF + hh * FD + f4 * 4;
    *(float4*)&q_s[ii][f4 * 4] = *(const float4*)p;
  }
  __syncthreads();

  // ---- phase 1: scores ----
  {
    const int ii = t & 15;   // query row in tile
    const int jl = t >> 4;   // 0..15, each handles 32 consecutive j
    float qv[FD], wv[FD];
#pragma unroll
    for (int f4 = 0; f4 < 8; ++f4) {
      const float4 q4 = *(const float4*)&q_s[ii][f4 * 4];
      qv[4 * f4 + 0] = q4.x;
      qv[4 * f4 + 1] = q4.y;
      qv[4 * f4 + 2] = q4.z;
      qv[4 * f4 + 3] = q4.w;
      const float4 w4 = *(const float4*)&w_s[f4 * 4];
      wv[4 * f4 + 0] = w4.x;
      wv[4 * f4 + 1] = w4.y;
      wv[4 * f4 + 2] = w4.z;
      wv[4 * f4 + 3] = w4.w;
    }
    const float* glp = gl + (size_t)b * NN * HF + hh * FD;
    const int* adjp = adj + (size_t)(i0 + ii) * NN;
#pragma unroll 2
    for (int jj = 0; jj < 32; ++jj) {
      const int j = jl * 32 + jj;
      const float* p = glp + (size_t)j * HF;
      float e = 0.f;
#pragma unroll
      for (int f4 = 0; f4 < 8; ++f4) {
        const float4 g4 = *(const float4*)(p + f4 * 4);
        float x;
        x = g4.x + qv[4 * f4 + 0];
        e = fmaf(wv[4 * f4 + 0], fmaxf(x, NEG * x), e);
        x = g4.y + qv[4 * f4 + 1];
        e = fmaf(wv[4 * f4 + 1], fmaxf(x, NEG * x), e);
        x = g4.z + qv[4 * f4 + 2];
        e = fmaf(wv[4 * f4 + 2], fmaxf(x, NEG * x), e);
        x = g4.w + qv[4 * f4 + 3];
        e = fmaf(wv[4 * f4 + 3], fmaxf(x, NEG * x), e);
      }
      e_s[ii][j] = adjp[j] ? e : MASKV;
    }
  }
  __syncthreads();

  // ---- phase 2: row softmax ----
  {
    const int wave = t >> 6, lane = t & 63;
    const int row = wave * 4 + (lane >> 4);  // 4 rows per wave
    const int l16 = lane & 15;               // 16 lanes per row
    float m = MASKV;
#pragma unroll
    for (int c = 0; c < 32; ++c) m = fmaxf(m, e_s[row][l16 + 16 * c]);
#pragma unroll
    for (int off = 1; off < 16; off <<= 1) m = fmaxf(m, __shfl_xor(m, off));
    float s = 0.f;
#pragma unroll
    for (int c = 0; c < 32; ++c) {
      const float p = exp2f((e_s[row][l16 + 16 * c] - m) * LOG2E);
      e_s[row][l16 + 16 * c] = p;
      s += p;
    }
#pragma unroll
    for (int off = 1; off < 16; off <<= 1) s += __shfl_xor(s, off);
    if (l16 == 0) inv_l[row] = 1.f / s;
  }
  __syncthreads();

  // ---- phase 3: aggregation ----
  {
    const int half = t >> 7;       // j-range split
    const int ii = (t >> 3) & 15;  // query row
    const int f4 = t & 7;          // feature quad
    const float* grp = gr + (size_t)b * NN * HF + hh * FD + f4 * 4;
    float4 acc = make_float4(0.f, 0.f, 0.f, 0.f);
    const int j0 = half * 256;
#pragma unroll 4
    for (int j = j0; j < j0 + 256; ++j) {
      const float p = e_s[ii][j];
      const float4 v = *(const float4*)(grp + (size_t)j * HF);
      acc.x = fmaf(p, v.x, acc.x);
      acc.y = fmaf(p, v.y, acc.y);
      acc.z = fmaf(p, v.z, acc.z);
      acc.w = fmaf(p, v.w, acc.w);
    }
    __syncthreads();
    if (half) *(float4*)&q_s[ii][f4 * 4] = acc;
    __syncthreads();
    if (!half) {
      const float4 o = *(const float4*)&q_s[ii][f4 * 4];
      const float sc = inv_l[ii];
      float4 r;
      r.x = (acc.x + o.x) * sc;
      r.y = (acc.y + o.y) * sc;
      r.z = (acc.z + o.z) * sc;
      r.w = (acc.w + o.w) * sc;
      float* op = out + (size_t)(b * NN + i0 + ii) * HF + hh * FD + f4 * 4;
      *(float4*)op = r;
    }
  }
}

// ---------------------------------------------------------------------------
extern "C" void kernel_launch(void* const* d_in, const int* in_sizes, int n_in,
                              void* d_out, int out_size, void* d_ws,
                              size_t ws_size, hipStream_t stream) {
  const float* h = (const float*)d_in[0];
  const int* adj = (const int*)d_in[1];
  const float* Wl = (const float*)d_in[2];
  const float* Wr = (const float*)d_in[3];
  const float* aw = (const float*)d_in[4];
  float* out = (float*)d_out;

  float* gl = (float*)d_ws;                       // 2048*256 floats = 2MB
  float* gr = gl + (size_t)BB * NN * HF;          // next 2MB

  dim3 gg(BB * NN / 8, 2, 1);
  gemm_dual<<<gg, 256, 0, stream>>>(h, Wl, Wr, gl, gr);

  dim3 ga(NH, NN / 16, BB);
  gat_attn<<<ga, 256, 0, stream>>>(gl, gr, adj, aw, out);
}